// Round 9
// baseline (195.173 us; speedup 1.0000x reference)
//
#include <hip/hip_runtime.h>
#include <hip/hip_bf16.h>
#include <math.h>

// Problem constants
#define BB 2
#define SS 2048
#define DD 1024
#define HH 16
#define DHH 64
#define MM (BB * SS) // 4096

typedef float f32x4 __attribute__((ext_vector_type(4)));
typedef float f32x16 __attribute__((ext_vector_type(16)));
typedef __bf16 bf16x8 __attribute__((ext_vector_type(8)));
typedef unsigned int u32x2 __attribute__((ext_vector_type(2)));

#define N_QKV ((size_t)MM * DD)
#define N_W   ((size_t)DD * DD)

// ---- fallback scratch (used only if ws_size is too small) -----------------
__device__ unsigned short g_X [3][N_QKV];   // bf16 activations
__device__ unsigned short g_Q [N_QKV];      // bf16 Q*0.125*log2e  [m][n]
__device__ unsigned short g_K [N_QKV];      // bf16 K        [m][n]
__device__ unsigned short g_Vt[N_QKV];      // bf16 V^T [b][h][dh][s]
__device__ unsigned short g_Wt[3][N_W];     // bf16 Wt[n][k]

// fp32 -> bf16 RNE
__device__ __forceinline__ unsigned short f2bu(float f) {
    unsigned u = __float_as_uint(f);
    unsigned r = u + 0x7FFFu + ((u >> 16) & 1u);
    return (unsigned short)(r >> 16);
}

union FragU { uint4 u; bf16x8 v; unsigned short s[8]; };
static __device__ __forceinline__ bf16x8 ldfrag(const unsigned short* p) {
    FragU f; f.u = *(const uint4*)p; return f.v;
}

// pack two f32 -> one u32 of 2xbf16 (compiler emits v_cvt_pk_bf16_f32)
static __device__ __forceinline__ unsigned pkbf(float a, float b) {
    union { __bf16 h[2]; unsigned u; } w;
    w.h[0] = (__bf16)a; w.h[1] = (__bf16)b;
    return w.u;
}

// raw v_exp_f32 (arg already in log2 domain; ocml exp2f adds range-fixup VALU)
static __device__ __forceinline__ float fexp2(float x) {
#if __has_builtin(__builtin_amdgcn_exp2f)
    return __builtin_amdgcn_exp2f(x);
#else
    float r;
    asm("v_exp_f32 %0, %1" : "=v"(r) : "v"(x));
    return r;
#endif
}

// lane[i] <-> lane[i+32] half-exchange producing BOTH PV A-frag words:
//   new_a[l] = l<32 ? a[l]    : b[l-32]
//   new_b[l] = l<32 ? a[l+32] : b[l]
static __device__ __forceinline__ void plswap(unsigned &a, unsigned &b) {
#if __has_builtin(__builtin_amdgcn_permlane32_swap)
    u32x2 r = __builtin_amdgcn_permlane32_swap((int)a, (int)b, false, false);
    a = r[0]; b = r[1];
#else
    asm volatile("v_permlane32_swap_b32 %0, %1" : "+v"(a), "+v"(b));
#endif
}

// async global->LDS, 16B per lane; LDS dest = wave-uniform base + lane*16
static __device__ __forceinline__ void gload16(const unsigned short* g, unsigned short* l) {
    __builtin_amdgcn_global_load_lds(
        (const __attribute__((address_space(1))) unsigned int*)g,
        (__attribute__((address_space(3))) unsigned int*)l, 16, 0, 0);
}

// ---------------------------------------------------------------------------
// prep3: merged {activations fp32->bf16} + {Wt[n][k] = bf16(W[k][n])}.
// Grid (4096+256, 3): bx<4096 cvt (1024 elems/block), else 64x64 transpose.
__global__ __launch_bounds__(256) void prep3(
        const float* __restrict__ x0, const float* __restrict__ x1,
        const float* __restrict__ x2, unsigned short* __restrict__ X,
        const float* __restrict__ W0, const float* __restrict__ W1,
        const float* __restrict__ W2, unsigned short* __restrict__ Wt3)
{
    __shared__ float Ts[64][65];
    const int z = blockIdx.y, t = threadIdx.x;
    if (blockIdx.x < 4096) {
        const float* src = z == 0 ? x0 : (z == 1 ? x1 : x2);
        unsigned short* dst = X + (size_t)z * N_QKV;
        const size_t i = ((size_t)blockIdx.x * 256 + t) * 4;
        const float4 v = *(const float4*)(src + i);
        ushort4 s;
        s.x = f2bu(v.x); s.y = f2bu(v.y); s.z = f2bu(v.z); s.w = f2bu(v.w);
        *(ushort4*)(dst + i) = s;
    } else {
        const float* W = z == 0 ? W0 : (z == 1 ? W1 : W2);
        unsigned short* Wt = Wt3 + (size_t)z * N_W;
        const int bx = blockIdx.x - 4096;
        const int k0 = (bx >> 4) * 64, n0 = (bx & 15) * 64;
#pragma unroll
        for (int i = 0; i < 16; ++i) {
            const int f = t + 256 * i, r = f >> 6, c = f & 63;
            Ts[r][c] = W[(size_t)(k0 + r) * DD + n0 + c];
        }
        __syncthreads();
#pragma unroll
        for (int i = 0; i < 16; ++i) {
            const int f = t + 256 * i, r = f >> 6, c = f & 63;
            Wt[(size_t)(n0 + r) * DD + k0 + c] = f2bu(Ts[c][r]);
        }
    }
}

// ---------------------------------------------------------------------------
// proj4: proj3 re-staged via global_load_lds width=16 (the m97 ladder step,
// +69% on this chip). z=0 Q (scale (1/8)*log2e), z=1 K, z=2 V^T.
//   - LDS linear [128][64]; staging: 4 gload16/wave per operand per K-step
//     (wave-uniform LDS base, per-lane swizzled GLOBAL source -- rule #21:
//     linear dest + inverse-swz source + swz read).
//   - swizzle f(r) = (r ^ (r>>3)) & 7 on the 16B slot (proven conflict-free
//     in attn8: SQ_LDS_BANK_CONFLICT -> 0). Fragment reads: 16 lanes/slot
//     spread over 8 slot-columns -> 2-way b128 aliasing (free, m136).
//   - m97 2-barrier single-buffer schedule; staging VALU + 32 VGPR freed.
// 1D grid 768, XCD-aware decode (T1).
__global__ __launch_bounds__(256) void proj4(
        const unsigned short* __restrict__ X, const unsigned short* __restrict__ Wt3,
        const float* __restrict__ bq, const float* __restrict__ bk,
        const float* __restrict__ bv,
        unsigned short* __restrict__ Qp, unsigned short* __restrict__ Kp,
        unsigned short* __restrict__ Vtp)
{
    // decode: x = XCD, zm = (z,m) pair; each XCD owns 12 zm x 8 n = 96 blocks
    const int bid = blockIdx.x;
    const int xx = bid & 7, j = bid >> 3;      // j 0..95
    const int zm = xx * 12 + (j >> 3);         // 0..95
    const int z  = zm >> 5;                    // 0..2
    const int m0 = (zm & 31) * 128;
    const int n0 = (j & 7) * 128;

    const unsigned short* xb = X   + (size_t)z * N_QKV;
    const unsigned short* Wt = Wt3 + (size_t)z * N_W;
    const float* bias = z == 0 ? bq : (z == 1 ? bk : bv);
    const float scale = z == 0 ? 0.18033688011112042f : 1.0f; // 0.125*log2(e)

    __shared__ unsigned short As[128][64];
    __shared__ unsigned short Bs[128][64];
    const int t = threadIdx.x, lane = t & 63, w = t >> 6;
    const int q = lane >> 4, li = lane & 15;
    const int wm = (w >> 1) * 64, wn = (w & 1) * 64;

    // staging: instr jj (0..3) of wave w covers rows (jj*4+w)*8 .. +7;
    // lane l -> row r0 + l/8, LDS slot l%8; source slot = (l%8) ^ f(row)
    const int lrow = lane >> 3, lslot = lane & 7;
    const unsigned short* gA[4];
    const unsigned short* gB[4];
    unsigned short* lA[4];
    unsigned short* lB[4];
#pragma unroll
    for (int jj = 0; jj < 4; ++jj) {
        const int r0 = (jj * 4 + w) * 8;
        const int row = r0 + lrow;
        const int ss = lslot ^ ((row ^ (row >> 3)) & 7);
        gA[jj] = xb + (size_t)(m0 + row) * DD + ss * 8;
        gB[jj] = Wt + (size_t)(n0 + row) * DD + ss * 8;
        lA[jj] = &As[r0][0];
        lB[jj] = &Bs[r0][0];
    }

#define ISSUE(kk) \
    _Pragma("unroll") \
    for (int jj = 0; jj < 4; ++jj) { \
        gload16(gA[jj] + (kk), lA[jj]); \
        gload16(gB[jj] + (kk), lB[jj]); \
    }

    f32x4 acc[4][4];
#pragma unroll
    for (int mt = 0; mt < 4; ++mt)
#pragma unroll
        for (int nt = 0; nt < 4; ++nt) acc[mt][nt] = (f32x4)0.f;

    ISSUE(0)

    for (int kk = 0; kk < DD; kk += 64) {
        __syncthreads();                       // vmcnt drained -> tile visible
#pragma unroll
        for (int ks8 = 0; ks8 < 8; ks8 += 4) { // ks = ks8*8
            bf16x8 a[4], b[4];
#pragma unroll
            for (int mt = 0; mt < 4; ++mt) {
                const int row = wm + mt * 16 + li;
                a[mt] = ldfrag(&As[row][((q + ks8) ^ ((row ^ (row >> 3)) & 7)) * 8]);
            }
#pragma unroll
            for (int nt = 0; nt < 4; ++nt) {
                const int row = wn + nt * 16 + li;
                b[nt] = ldfrag(&Bs[row][((q + ks8) ^ ((row ^ (row >> 3)) & 7)) * 8]);
            }
#pragma unroll
            for (int mt = 0; mt < 4; ++mt)
#pragma unroll
                for (int nt = 0; nt < 4; ++nt)
                    acc[mt][nt] = __builtin_amdgcn_mfma_f32_16x16x32_bf16(
                        a[mt], b[nt], acc[mt][nt], 0, 0, 0);
        }
        __syncthreads();                       // reads done before overwrite
        if (kk + 64 < DD) { ISSUE(kk + 64) }
    }
#undef ISSUE

    float bvv[4];
#pragma unroll
    for (int nt = 0; nt < 4; ++nt) bvv[nt] = bias[n0 + wn + nt * 16 + li];

    if (z < 2) {
        unsigned short* out = z == 0 ? Qp : Kp;
#pragma unroll
        for (int mt = 0; mt < 4; ++mt)
#pragma unroll
            for (int nt = 0; nt < 4; ++nt)
#pragma unroll
                for (int reg = 0; reg < 4; ++reg) {
                    const int m = m0 + wm + mt * 16 + q * 4 + reg;
                    out[(size_t)m * DD + n0 + wn + nt * 16 + li] =
                        f2bu((acc[mt][nt][reg] + bvv[nt]) * scale);
                }
    } else {
        const int b = m0 >> 11;          // 128-row m-tiles never cross batch
        const int h = (n0 + wn) >> 6;    // 64-wide wave n-slice == one head
#pragma unroll
        for (int mt = 0; mt < 4; ++mt)
#pragma unroll
            for (int nt = 0; nt < 4; ++nt) {
                const int s = (m0 & (SS - 1)) + wm + mt * 16 + q * 4;
                const int dh = nt * 16 + li;
                ushort4 sv;
                sv.x = f2bu(acc[mt][nt][0] + bvv[nt]);
                sv.y = f2bu(acc[mt][nt][1] + bvv[nt]);
                sv.z = f2bu(acc[mt][nt][2] + bvv[nt]);
                sv.w = f2bu(acc[mt][nt][3] + bvv[nt]);
                *(ushort4*)(Vtp + ((size_t)((b * HH + h) * DHH + dh)) * SS + s) = sv;
            }
    }
}

// ---------------------------------------------------------------------------
// attn11: 256 q-rows/block, 8 waves, ONE shared KV stream, quad-buffered.
// (unchanged from R8: 53.0us, MfmaUtil 26.5, conflicts 0)
// Grid (256), 512 threads.
__global__ __launch_bounds__(512, 1) void attn11(
        const unsigned short* __restrict__ Qg, const unsigned short* __restrict__ Kg,
        const unsigned short* __restrict__ Vtg,
        const float* __restrict__ queries, float* __restrict__ outp)
{
    __shared__ unsigned short Kb[4][64][64];   // 32KB
    __shared__ unsigned short Vb[4][64][64];   // 32KB
    __shared__ float Lp[8][32];                // 1KB

    const int t = threadIdx.x, lane = t & 63, w = t >> 6;   // w 0..7
    const int col = lane & 31;          // q-row (QK) / dh (PV) owned by lane
    const int hi  = lane >> 5;

    // XCD decode: x = bid&7 owns (b,h) pairs {4x .. 4x+3}; all 8 qt-blocks
    // of a pair share that XCD's L2.
    const int bid = blockIdx.x;
    const int p  = (bid & 7) * 4 + ((bid >> 3) >> 3);   // pair 0..31
    const int qt = (bid >> 3) & 7;                      // 0..7 (256-row tiles)
    const int h = p & 15, b = p >> 4;

    const int sr = t >> 3;              // staging row 0..63
    const int sc = t & 7;               // staging 16B slot

    const unsigned short* Kbase = Kg  + (size_t)(b * SS) * DD + h * DHH;
    const unsigned short* Vbase = Vtg + ((size_t)((b * HH + h) * DHH)) * SS;

    // Q fragments: lane holds Q[q = qt*256 + w*32 + col][d = i*16 + hi*8 + j]
    bf16x8 qa[4];
    {
        const unsigned short* qp =
            Qg + (size_t)(b * SS + qt * 256 + w * 32 + col) * DD + h * DHH + hi * 8;
#pragma unroll
        for (int i = 0; i < 4; ++i) qa[i] = ldfrag(qp + i * 16);
    }

    f32x16 o0 = (f32x16)0.f, o1 = (f32x16)0.f;
    float lsum = 0.f;
    // two-level swizzle keys: f(row) = (row ^ (row>>3)) & 7
    const int xr2 = (col ^ (col >> 3)) & 7;    // read key row col; col+32 -> ^4
    const int wsw = (sr ^ (sr >> 3)) & 7;      // write key for row sr (0..63)

    // two register sets, 2 tiles each (K+V per tile)
    uint4 aK0, aV0, aK1, aV1, bK0, bV0, bK1, bV1;
#define LD2(K0, V0, K1, V1, s0) \
    K0 = *(const uint4*)(Kbase + (size_t)((s0)      + sr) * DD + sc * 8); \
    V0 = *(const uint4*)(Vbase + (size_t)sr * SS + (s0)      + sc * 8); \
    K1 = *(const uint4*)(Kbase + (size_t)((s0) + 64 + sr) * DD + sc * 8); \
    V1 = *(const uint4*)(Vbase + (size_t)sr * SS + (s0) + 64 + sc * 8);

#define ST2(K0, V0, K1, V1, b0, b1) \
    *(uint4*)&Kb[b0][sr][(sc ^ wsw) * 8] = K0; \
    *(uint4*)&Vb[b0][sr][(sc ^ wsw) * 8] = V0; \
    *(uint4*)&Kb[b1][sr][(sc ^ wsw) * 8] = K1; \
    *(uint4*)&Vb[b1][sr][(sc ^ wsw) * 8] = V1;

// one 64-k tile from LDS buffer BUF (compile-time)
#define TILE(BUF)                                                             \
    {                                                                         \
        f32x16 st0 = (f32x16)0.f, st1 = (f32x16)0.f;                          \
        __builtin_amdgcn_s_setprio(1);                                        \
        _Pragma("unroll")                                                     \
        for (int i = 0; i < 4; ++i) {                                         \
            const int sl = (i * 2 + hi) ^ xr2;                                \
            bf16x8 ka0 = ldfrag(&Kb[BUF][col     ][sl * 8]);                  \
            bf16x8 ka1 = ldfrag(&Kb[BUF][col + 32][(sl ^ 4) * 8]);            \
            st0 = __builtin_amdgcn_mfma_f32_32x32x16_bf16(ka0, qa[i], st0, 0, 0, 0); \
            st1 = __builtin_amdgcn_mfma_f32_32x32x16_bf16(ka1, qa[i], st1, 0, 0, 0); \
        }                                                                     \
        __builtin_amdgcn_s_setprio(0);                                        \
        unsigned pkw[4][4];                                                   \
        float ls = 0.f;                                                       \
        _Pragma("unroll")                                                     \
        for (int s = 0; s < 2; ++s) {                                         \
            float pe[8];                                                      \
            _Pragma("unroll")                                                 \
            for (int r = 0; r < 8; ++r) pe[r] = fexp2(st0[8 * s + r]);        \
            ls += ((pe[0] + pe[1]) + (pe[2] + pe[3])) + ((pe[4] + pe[5]) + (pe[6] + pe[7])); \
            pkw[s][0] = pkbf(pe[0], pe[1]); pkw[s][1] = pkbf(pe[2], pe[3]);   \
            pkw[s][2] = pkbf(pe[4], pe[5]); pkw[s][3] = pkbf(pe[6], pe[7]);   \
        }                                                                     \
        _Pragma("unroll")                                                     \
        for (int s = 0; s < 2; ++s) {                                         \
            float pe[8];                                                      \
            _Pragma("unroll")                                                 \
            for (int r = 0; r < 8; ++r) pe[r] = fexp2(st1[8 * s + r]);        \
            ls += ((pe[0] + pe[1]) + (pe[2] + pe[3])) + ((pe[4] + pe[5]) + (pe[6] + pe[7])); \
            pkw[2 + s][0] = pkbf(pe[0], pe[1]); pkw[2 + s][1] = pkbf(pe[2], pe[3]); \
            pkw[2 + s][2] = pkbf(pe[4], pe[5]); pkw[2 + s][3] = pkbf(pe[6], pe[7]); \
        }                                                                     \
        lsum += ls;                                                           \
        __builtin_amdgcn_s_setprio(1);                                        \
        _Pragma("unroll")                                                     \
        for (int c = 0; c < 4; ++c) {                                         \
            unsigned A0 = pkw[c][0], B0 = pkw[c][2];                          \
            unsigned A1 = pkw[c][1], B1 = pkw[c][3];                          \
            plswap(A0, B0); plswap(A1, B1);                                   \
            FragU pf;                                                         \
            pf.u.x = A0; pf.u.y = A1; pf.u.z = B0; pf.u.w = B1;               \
            const int vl = (c * 2 + hi) ^ xr2;                                \
            bf16x8 vb0 = ldfrag(&Vb[BUF][col     ][vl * 8]);                  \
            bf16x8 vb1 = ldfrag(&Vb[BUF][col + 32][(vl ^ 4) * 8]);            \
            o0 = __builtin_amdgcn_mfma_f32_32x32x16_bf16(pf.v, vb0, o0, 0, 0, 0); \
            o1 = __builtin_amdgcn_mfma_f32_32x32x16_bf16(pf.v, vb1, o1, 0, 0, 0); \
        }                                                                     \
        __builtin_amdgcn_s_setprio(0);                                        \
    }

    // prologue: tiles 0,1 -> bufs 0,1 ; tiles 2,3 in regs (set b)
    LD2(aK0, aV0, aK1, aV1, 0)
    ST2(aK0, aV0, aK1, aV1, 0, 1)
    LD2(bK0, bV0, bK1, bV1, 128)
    __syncthreads();

    // 8 iterations x 2 bodies; body = 2 tiles (128 k) + 1 barrier
    for (int tt = 0; tt < SS; tt += 256) {
        // bodyA: compute bufs 0,1 (tiles tt, tt+64); LDa(tt+256,tt+320);
        //        ST set b (tiles tt+128,tt+192) -> bufs 2,3
        if (tt + 256 < SS) { LD2(aK0, aV0, aK1, aV1, tt + 256) }
        TILE(0)
        ST2(bK0, bV0, bK1, bV1, 2, 3)
        TILE(1)
        __syncthreads();
        // bodyB: compute bufs 2,3; LDb(tt+384,tt+448); ST set a -> bufs 0,1
        if (tt + 384 < SS) { LD2(bK0, bV0, bK1, bV1, tt + 384) }
        TILE(2)
        if (tt + 256 < SS) { ST2(aK0, aV0, aK1, aV1, 0, 1) }
        TILE(3)
        if (tt + 256 < SS) __syncthreads();
    }
#undef TILE
#undef LD2
#undef ST2

    // epilogue: l = full-row sum; broadcast 1/l via LDS
    const float lt = lsum + __shfl_xor(lsum, 32);
    if (lane < 32) Lp[w][lane] = lt;
    __syncthreads();

    // rows = crow(reg,hi), cols = lane&31 (+32 for o1)
    const size_t gbase = (size_t)(b * SS + qt * 256 + w * 32) * DD + h * DHH + col;
#pragma unroll
    for (int reg = 0; reg < 16; ++reg) {
        const int rl = (reg & 3) + 8 * (reg >> 2) + 4 * hi;
        const float li = 1.f / Lp[w][rl];
        const size_t g = gbase + (size_t)rl * DD;
        outp[g]      = o0[reg] * li + queries[g];
        outp[g + 32] = o1[reg] * li + queries[g + 32];
    }
}

// ---------------------------------------------------------------------------
extern "C" void kernel_launch(void* const* d_in, const int* in_sizes, int n_in,
                              void* d_out, int out_size, void* d_ws, size_t ws_size,
                              hipStream_t stream) {
    const float* queries = (const float*)d_in[0];
    const float* keys    = (const float*)d_in[1];
    const float* values  = (const float*)d_in[2];
    const float* Wq      = (const float*)d_in[3];
    const float* bq      = (const float*)d_in[4];
    const float* Wk      = (const float*)d_in[5];
    const float* bk      = (const float*)d_in[6];
    const float* Wv      = (const float*)d_in[7];
    const float* bv      = (const float*)d_in[8];
    float* outp = (float*)d_out;

    // scratch: prefer d_ws (54 MB needed); fall back to device globals.
    const size_t need = (6 * N_QKV + 3 * N_W) * sizeof(unsigned short);
    unsigned short *Xp, *Qp, *Kp, *Vtp, *Wtp;
    if (ws_size >= need) {
        Xp  = (unsigned short*)d_ws;
        Qp  = Xp + 3 * N_QKV;
        Kp  = Qp + N_QKV;
        Vtp = Kp + N_QKV;
        Wtp = Vtp + N_QKV;
    } else {
        hipGetSymbolAddress((void**)&Xp,  HIP_SYMBOL(g_X));
        hipGetSymbolAddress((void**)&Qp,  HIP_SYMBOL(g_Q));
        hipGetSymbolAddress((void**)&Kp,  HIP_SYMBOL(g_K));
        hipGetSymbolAddress((void**)&Vtp, HIP_SYMBOL(g_Vt));
        hipGetSymbolAddress((void**)&Wtp, HIP_SYMBOL(g_Wt));
    }

    const dim3 bp(256);
    prep3<<<dim3(4096 + 256, 3), bp, 0, stream>>>(queries, keys, values, Xp,
                                                  Wq, Wk, Wv, Wtp);
    proj4<<<dim3(768), bp, 0, stream>>>(Xp, Wtp, bq, bk, bv, Qp, Kp, Vtp);
    attn11<<<dim3(256), dim3(512), 0, stream>>>(Qp, Kp, Vtp, queries, outp);
}